// Round 5
// baseline (63.921 us; speedup 1.0000x reference)
//
#include <hip/hip_runtime.h>

// out[t*768 + e] = weight[e*VOCAB + x[t]]
// Single fused kernel. One block per (32-col window, 192-row group):
//   1. stage 192x32 f32 weight slab into LDS (coalesced float4, pad-33)
//   2. filter the whole 16K-token array (64KB, L2-hot) against this window,
//      compacting matches into an LDS list via LDS atomics (overlaps staging)
//   3. one barrier, then serve tokens from LDS with 256B-coalesced stores.
// Fallback (any window bucket > CAP, adversarial only): chunked re-filter.

#define VOCAB 50257
#define EMBED 768
#define WINB 32
#define NWIN 1571          // ceil(VOCAB/32)
#define RG 4               // row groups
#define ROWS 192           // EMBED / RG
#define LSTRIDE 33         // +1 pad -> serve reads 2-way (free)
#define CAP 256

__device__ __forceinline__ int xcd_swizzle(int bid, int nwg) {
  const int NX = 8;                   // bijective m204 variant
  int q = nwg / NX, r = nwg % NX;
  int xcd = bid % NX, idx = bid / NX;
  int base = (xcd < r) ? xcd * (q + 1) : r * (q + 1) + (xcd - r) * q;
  return base + idx;
}

__global__ __launch_bounds__(256) void embed_kernel(const int* __restrict__ x,
                                                    const float* __restrict__ w,
                                                    float* __restrict__ out,
                                                    int n) {
  __shared__ float lds[ROWS * LSTRIDE];
  __shared__ int toks[CAP];
  __shared__ int cnt;
  const int logical = xcd_swizzle(blockIdx.x, NWIN * RG);
  const int wid = logical % NWIN;     // adjacent wids share an XCD chunk
  const int rg  = logical / NWIN;
  const int row0 = rg * ROWS;
  const int col0 = wid * WINB;
  const int tid = threadIdx.x;
  const int wave = tid >> 6, lane = tid & 63;

  if (tid == 0) cnt = 0;
  __syncthreads();

  // --- stage 192x32 slab, coalesced float4 (6 per thread) ---
  if (wid != NWIN - 1) {
    #pragma unroll
    for (int j = tid; j < ROWS * 8; j += 256) {
      int r = j >> 3, c4 = (j & 7) << 2;
      float4 v = *(const float4*)&w[(size_t)(row0 + r) * VOCAB + col0 + c4];
      float* d = &lds[r * LSTRIDE + c4];
      d[0] = v.x; d[1] = v.y; d[2] = v.z; d[3] = v.w;
    }
  } else {
    for (int j = tid; j < ROWS * 8; j += 256) {
      int r = j >> 3, c4 = (j & 7) << 2;
      float* d = &lds[r * LSTRIDE + c4];
      for (int u = 0; u < 4; ++u) {
        int c = col0 + c4 + u;
        d[u] = (c < VOCAB) ? w[(size_t)(row0 + r) * VOCAB + c] : 0.f;
      }
    }
  }

  // --- filter all tokens against this window (x is L2-resident) ---
  const int4* x4 = (const int4*)x;
  const int n4 = n >> 2;
  for (int j = tid; j < n4; j += 256) {
    int4 v = x4[j];
    int bt = j << 2;
    if ((v.x >> 5) == wid) { int p = atomicAdd(&cnt, 1); if (p < CAP) toks[p] = ((bt    ) << 5) | (v.x & 31); }
    if ((v.y >> 5) == wid) { int p = atomicAdd(&cnt, 1); if (p < CAP) toks[p] = ((bt + 1) << 5) | (v.y & 31); }
    if ((v.z >> 5) == wid) { int p = atomicAdd(&cnt, 1); if (p < CAP) toks[p] = ((bt + 2) << 5) | (v.z & 31); }
    if ((v.w >> 5) == wid) { int p = atomicAdd(&cnt, 1); if (p < CAP) toks[p] = ((bt + 3) << 5) | (v.w & 31); }
  }
  for (int j = (n4 << 2) + tid; j < n; j += 256) {   // tail (n % 4)
    int v = x[j];
    if ((v >> 5) == wid) { int p = atomicAdd(&cnt, 1); if (p < CAP) toks[p] = (j << 5) | (v & 31); }
  }
  __syncthreads();

  const int m = cnt;
  if (m <= CAP) {
    // --- fast path: serve all bucket tokens from LDS ---
    for (int i = wave; i < m; i += 4) {
      int pk = toks[i];               // LDS broadcast
      int t = pk >> 5, c = pk & 31;
      float* o = &out[(size_t)t * EMBED + row0];
      #pragma unroll
      for (int k = 0; k < 3; ++k)     // bank=(lane+c)%32 -> 2-way, free
        o[k * 64 + lane] = lds[(k * 64 + lane) * LSTRIDE + c];
    }
  } else {
    // --- adversarial fallback: chunked re-filter (never on random data) ---
    __syncthreads();
    for (int c0 = 0; c0 < n; c0 += CAP) {
      if (tid == 0) cnt = 0;
      __syncthreads();
      int c1 = (c0 + CAP < n) ? c0 + CAP : n;
      for (int j = c0 + tid; j < c1; j += 256) {
        int v = x[j];
        if ((v >> 5) == wid) { int p = atomicAdd(&cnt, 1); toks[p] = (j << 5) | (v & 31); }
      }
      __syncthreads();
      int mm = cnt;
      for (int i = wave; i < mm; i += 4) {
        int pk = toks[i];
        int t = pk >> 5, c = pk & 31;
        float* o = &out[(size_t)t * EMBED + row0];
        #pragma unroll
        for (int k = 0; k < 3; ++k)
          o[k * 64 + lane] = lds[(k * 64 + lane) * LSTRIDE + c];
      }
      __syncthreads();
    }
  }
}

extern "C" void kernel_launch(void* const* d_in, const int* in_sizes, int n_in,
                              void* d_out, int out_size, void* d_ws, size_t ws_size,
                              hipStream_t stream) {
  const int*   x = (const int*)d_in[0];
  const float* w = (const float*)d_in[1];
  float* out = (float*)d_out;
  const int n = in_sizes[0];          // 16384 tokens

  embed_kernel<<<NWIN * RG, 256, 0, stream>>>(x, w, out, n);
}

// Round 6
// 49.634 us; speedup vs baseline: 1.2878x; 1.2878x over previous
//
#include <hip/hip_runtime.h>

// out[t*768 + e] = weight[e*VOCAB + x[t]]
// Pipeline: memset(cur) -> scatter tokens into fixed-cap per-window buckets
// (cap 64; Poisson(10.4) mean occupancy, overflow -> spill list) -> gather:
// one block per (32-col window, 192-row group) stages the 192x32 weight slab
// to LDS (coalesced float4, pad-33 => conflict-free serve) and writes each
// bucket token's rows with 256B-coalesced nontemporal stores -> spill cleanup
// (no-op unless adversarial input overflowed a bucket).

#define VOCAB 50257
#define EMBED 768
#define WINB 32
#define NWIN 1571          // ceil(VOCAB/32)
#define RG 4               // row groups
#define ROWS 192           // EMBED / RG
#define LSTRIDE 33         // +1 pad -> serve reads bank=(lane+c)%32, 2-way free
#define CAP 64             // bucket capacity (mean load 10.4)

__device__ __forceinline__ int xcd_swizzle(int bid, int nwg) {
  const int NX = 8;                   // bijective m204 variant
  int q = nwg / NX, r = nwg % NX;
  int xcd = bid % NX, idx = bid / NX;
  int base = (xcd < r) ? xcd * (q + 1) : r * (q + 1) + (xcd - r) * q;
  return base + idx;
}

__global__ __launch_bounds__(256) void scatter_kernel(const int* __restrict__ x,
                                                      int* __restrict__ cur,
                                                      int* __restrict__ buckets,
                                                      int* __restrict__ spill_cnt,
                                                      int* __restrict__ spill,
                                                      int n) {
  int i = blockIdx.x * blockDim.x + threadIdx.x;
  if (i < n) {
    int v = x[i];
    int win = v >> 5;
    int p = atomicAdd(&cur[win], 1);
    if (p < CAP) {
      buckets[win * CAP + p] = (i << 5) | (v & 31);
    } else {
      int s = atomicAdd(spill_cnt, 1);
      spill[s] = (i << 16) | v;       // t:14b | v:16b
    }
  }
}

__global__ __launch_bounds__(256) void gather_kernel(const float* __restrict__ w,
                                                     const int* __restrict__ cur,
                                                     const int* __restrict__ buckets,
                                                     float* __restrict__ out) {
  __shared__ float lds[ROWS * LSTRIDE];
  __shared__ int toks[CAP];
  const int logical = xcd_swizzle(blockIdx.x, NWIN * RG);
  const int wid = logical % NWIN;     // adjacent wids share an XCD chunk
  const int rg  = logical / NWIN;
  const int row0 = rg * ROWS;
  const int col0 = wid * WINB;
  const int tid = threadIdx.x;
  const int wave = tid >> 6, lane = tid & 63;

  int m = cur[wid];                   // uniform scalar load
  if (m > CAP) m = CAP;

  // token list: single conditional load, overlaps staging
  if (tid < m) toks[tid] = buckets[wid * CAP + tid];

  // --- stage 192x32 slab, coalesced float4 (6 per thread) ---
  if (wid != NWIN - 1) {
    #pragma unroll
    for (int j = tid; j < ROWS * 8; j += 256) {
      int r = j >> 3, c4 = (j & 7) << 2;
      float4 v = *(const float4*)&w[(size_t)(row0 + r) * VOCAB + col0 + c4];
      float* d = &lds[r * LSTRIDE + c4];
      d[0] = v.x; d[1] = v.y; d[2] = v.z; d[3] = v.w;
    }
  } else {
    for (int j = tid; j < ROWS * 8; j += 256) {
      int r = j >> 3, c4 = (j & 7) << 2;
      float* d = &lds[r * LSTRIDE + c4];
      for (int u = 0; u < 4; ++u) {
        int c = col0 + c4 + u;
        d[u] = (c < VOCAB) ? w[(size_t)(row0 + r) * VOCAB + c] : 0.f;
      }
    }
  }
  __syncthreads();

  // --- serve bucket tokens from LDS; nontemporal 256B-coalesced stores ---
  for (int i = wave; i < m; i += 4) {
    int pk = toks[i];                 // LDS broadcast
    int t = pk >> 5, c = pk & 31;
    float* o = &out[(size_t)t * EMBED + row0];
    #pragma unroll
    for (int k = 0; k < 3; ++k)
      __builtin_nontemporal_store(lds[(k * 64 + lane) * LSTRIDE + c],
                                  &o[k * 64 + lane]);
  }
}

// adversarial-only cleanup: immediate exit when spill_cnt == 0
__global__ __launch_bounds__(256) void spill_kernel(const float* __restrict__ w,
                                                    const int* __restrict__ spill_cnt,
                                                    const int* __restrict__ spill,
                                                    float* __restrict__ out) {
  int cnt = *spill_cnt;
  for (int s = blockIdx.x; s < cnt; s += gridDim.x) {
    int pk = spill[s];
    int t = pk >> 16, v = pk & 0xFFFF;
    for (int e = threadIdx.x; e < EMBED; e += 256)
      out[(size_t)t * EMBED + e] = w[(size_t)e * VOCAB + v];
  }
}

extern "C" void kernel_launch(void* const* d_in, const int* in_sizes, int n_in,
                              void* d_out, int out_size, void* d_ws, size_t ws_size,
                              hipStream_t stream) {
  const int*   x = (const int*)d_in[0];
  const float* w = (const float*)d_in[1];
  float* out = (float*)d_out;
  const int n = in_sizes[0];          // 16384 tokens

  int* cur       = (int*)d_ws;            // [NWIN]
  int* spill_cnt = cur + NWIN;             // [1]
  int* spill     = spill_cnt + 1;          // [n]
  int* buckets   = spill + n;              // [NWIN*CAP]

  hipMemsetAsync(cur, 0, (NWIN + 1) * sizeof(int), stream);
  scatter_kernel<<<(n + 255) / 256, 256, 0, stream>>>(x, cur, buckets,
                                                      spill_cnt, spill, n);
  gather_kernel<<<NWIN * RG, 256, 0, stream>>>(w, cur, buckets, out);
  spill_kernel<<<64, 256, 0, stream>>>(w, spill_cnt, spill, out);
}